// Round 5
// baseline (278.797 us; speedup 1.0000x reference)
//
#include <hip/hip_runtime.h>
#include <stdint.h>

#define B_ 2
#define S_ 2048
#define D_ 1024
#define H_ 16
#define HD_ 64
#define M_ (B_*S_)   // 4096

typedef __bf16 bf16;
typedef __attribute__((ext_vector_type(8))) __bf16 bf16x8;
typedef __attribute__((ext_vector_type(4))) float f32x4;
typedef __attribute__((ext_vector_type(2))) float f32x2;

// async global->LDS, 16B per lane. LDS dest = uniform base + lane*16.
__device__ __forceinline__ void gload16(const bf16* g, bf16* l) {
    __builtin_amdgcn_global_load_lds(
        (const __attribute__((address_space(1))) void*)g,
        (__attribute__((address_space(3))) void*)l, 16, 0, 0);
}

// ---------------- fp32 -> bf16 converts (single launch) ----------------
__global__ void k_cvt_all(const float* __restrict__ hs,
                          const float* __restrict__ Wq, const float* __restrict__ Wk,
                          const float* __restrict__ Wv, const float* __restrict__ Wo,
                          bf16* __restrict__ hb,
                          bf16* __restrict__ wqb, bf16* __restrict__ wkb,
                          bf16* __restrict__ wvb, bf16* __restrict__ wob) {
    int blk = blockIdx.x;
    const float* s; bf16* d; int base;
    if (blk < 2048) { s = hs; d = hb; base = blk; }
    else {
        int r = blk - 2048; int which = r >> 9; base = r & 511;
        s = (which==0)?Wq:(which==1)?Wk:(which==2)?Wv:Wo;
        d = (which==0)?wqb:(which==1)?wkb:(which==2)?wvb:wob;
    }
    int idx = base*2048 + threadIdx.x*8;
    float4 a = *(const float4*)(s + idx);
    float4 b = *(const float4*)(s + idx + 4);
    bf16 o[8] = {(bf16)a.x,(bf16)a.y,(bf16)a.z,(bf16)a.w,
                 (bf16)b.x,(bf16)b.y,(bf16)b.z,(bf16)b.w};
    *(int4*)(d + idx) = *(const int4*)o;
}

// ---------------- QKV projection GEMM (coalesced LDS-transpose epilogue) ----
// z=0: Q -> [BH][S][HD] scaled 1/8 ; z=1: K -> [BH][S][HD] ; z=2: V -> [BH][HD][S]
__global__ __launch_bounds__(256) void k_gemm_qkv(
    const bf16* __restrict__ X,
    const bf16* __restrict__ Wq, const bf16* __restrict__ Wk, const bf16* __restrict__ Wv,
    const float* __restrict__ bq, const float* __restrict__ bk, const float* __restrict__ bv,
    bf16* __restrict__ Qo, bf16* __restrict__ Ko, bf16* __restrict__ Vo)
{
    const int z = blockIdx.z;
    const bf16* W = (z==0) ? Wq : (z==1) ? Wk : Wv;
    const float* bias = (z==0) ? bq : (z==1) ? bk : bv;
    const int n0 = blockIdx.x * 128;
    const int m0 = blockIdx.y * 128;
    const int t = threadIdx.x;
    const int w = t >> 6, lane = t & 63, quad = lane >> 4, l15 = lane & 15;
    const int lr = lane >> 3;
    const int lc = (lane & 7) ^ lr;
    const int sx = l15 & 7;
    const int mw = (w >> 1) * 64, nw = (w & 1) * 64;

    __shared__ __align__(16) char smraw[128*136*2];  // 34816 B, aliased
    bf16* As  = (bf16*)smraw;               // [128][64]
    bf16* Bs  = (bf16*)(smraw + 16384);     // [128][64]
    bf16* epi = (bf16*)smraw;               // [128][136]

    f32x4 acc[4][4];
    #pragma unroll
    for (int i = 0; i < 4; i++)
        #pragma unroll
        for (int j = 0; j < 4; j++)
            acc[i][j] = (f32x4){0.f,0.f,0.f,0.f};

    const bf16* gA = X + (size_t)(m0 + w*8 + lr)*D_ + lc*8;
    const bf16* gB = W + (size_t)(n0 + w*8 + lr)*D_ + lc*8;

    for (int k0 = 0; k0 < D_; k0 += 64) {
        #pragma unroll
        for (int c = 0; c < 4; c++) {
            gload16(gA + (size_t)c*32*D_ + k0, &As[c*2048 + w*512]);
            gload16(gB + (size_t)c*32*D_ + k0, &Bs[c*2048 + w*512]);
        }
        __syncthreads();
        #pragma unroll
        for (int ks = 0; ks < 2; ks++) {
            bf16x8 af[4], bfr[4];
            #pragma unroll
            for (int i = 0; i < 4; i++)
                af[i] = *(const bf16x8*)&As[(mw + i*16 + l15)*64 + (((ks*4+quad)^sx)*8)];
            #pragma unroll
            for (int j = 0; j < 4; j++)
                bfr[j] = *(const bf16x8*)&Bs[(nw + j*16 + l15)*64 + (((ks*4+quad)^sx)*8)];
            #pragma unroll
            for (int i = 0; i < 4; i++)
                #pragma unroll
                for (int j = 0; j < 4; j++)
                    acc[i][j] = __builtin_amdgcn_mfma_f32_16x16x32_bf16(af[i], bfr[j], acc[i][j], 0, 0, 0);
        }
        __syncthreads();
    }

    // ---- epilogue: acc -> LDS (transposed layouts) -> coalesced global ----
    const float scale = (z == 0) ? 0.125f : 1.0f;
    if (z == 2) {
        #pragma unroll
        for (int j = 0; j < 4; j++) {
            int n = nw + j*16 + l15;
            float bn = bias[n0 + n];
            #pragma unroll
            for (int i = 0; i < 4; i++) {
                int mloc = mw + i*16 + quad*4;
                union { bf16 h4[4]; uint2 u; } pk;
                #pragma unroll
                for (int r = 0; r < 4; r++) pk.h4[r] = (bf16)(acc[i][j][r] + bn);
                *(uint2*)&epi[n*136 + mloc] = pk.u;
            }
        }
    } else {
        #pragma unroll
        for (int j = 0; j < 4; j++) {
            int n = nw + j*16 + l15;
            float bn = bias[n0 + n];
            #pragma unroll
            for (int i = 0; i < 4; i++) {
                int mloc = mw + i*16 + quad*4;
                #pragma unroll
                for (int r = 0; r < 4; r++)
                    epi[(mloc + r)*136 + n] = (bf16)((acc[i][j][r] + bn) * scale);
            }
        }
    }
    __syncthreads();
    if (z == 2) {
        #pragma unroll
        for (int kk = 0; kk < 8; kk++) {
            int c = t + 256*kk;
            int row = c >> 4;             // local n (dim)
            int mcol = (c & 15) * 8;      // local m (token)
            int4 val = *(const int4*)&epi[row*136 + mcol];
            int n = n0 + row; int hh = n >> 6, hd = n & 63;
            int m = m0 + mcol; int bb = m >> 11, s = m & 2047;
            *(int4*)&Vo[((size_t)((bb*H_ + hh)*HD_ + hd))*S_ + s] = val;
        }
    } else {
        bf16* Out = (z == 0) ? Qo : Ko;
        #pragma unroll
        for (int kk = 0; kk < 8; kk++) {
            int c = t + 256*kk;
            int row = c >> 4;             // local m (token)
            int ncol = (c & 15) * 8;      // local n (dim)
            int4 val = *(const int4*)&epi[row*136 + ncol];
            int m = m0 + row; int bb = m >> 11, s = m & 2047;
            int n = n0 + ncol; int hh = n >> 6, hd = n & 63;
            *(int4*)&Out[((size_t)((bb*H_ + hh)*S_ + s))*HD_ + hd] = val;
        }
    }
}

// ---------------- output projection GEMM (64x128 tile) ----------------
__global__ __launch_bounds__(256) void k_gemm_out(
    const bf16* __restrict__ X, const bf16* __restrict__ W,
    const float* __restrict__ bias, float* __restrict__ Out)
{
    const int n0 = blockIdx.x * 128;
    const int m0 = blockIdx.y * 64;
    const int t = threadIdx.x;
    const int w = t >> 6, lane = t & 63, quad = lane >> 4, l15 = lane & 15;
    const int lr = lane >> 3;
    const int lc = (lane & 7) ^ lr;
    const int sx = l15 & 7;
    const int nw = w * 32;

    __shared__ __align__(16) bf16 As[64*64];
    __shared__ __align__(16) bf16 Bs[128*64];

    f32x4 acc[4][2];
    #pragma unroll
    for (int i = 0; i < 4; i++)
        #pragma unroll
        for (int j = 0; j < 2; j++)
            acc[i][j] = (f32x4){0.f,0.f,0.f,0.f};

    const bf16* gA = X + (size_t)(m0 + w*8 + lr)*D_ + lc*8;
    const bf16* gB = W + (size_t)(n0 + w*8 + lr)*D_ + lc*8;

    for (int k0 = 0; k0 < D_; k0 += 64) {
        #pragma unroll
        for (int c = 0; c < 2; c++)
            gload16(gA + (size_t)c*32*D_ + k0, &As[c*2048 + w*512]);
        #pragma unroll
        for (int c = 0; c < 4; c++)
            gload16(gB + (size_t)c*32*D_ + k0, &Bs[c*2048 + w*512]);
        __syncthreads();
        #pragma unroll
        for (int ks = 0; ks < 2; ks++) {
            bf16x8 af[4], bfr[2];
            #pragma unroll
            for (int i = 0; i < 4; i++)
                af[i] = *(const bf16x8*)&As[(i*16 + l15)*64 + (((ks*4+quad)^sx)*8)];
            #pragma unroll
            for (int j = 0; j < 2; j++)
                bfr[j] = *(const bf16x8*)&Bs[(nw + j*16 + l15)*64 + (((ks*4+quad)^sx)*8)];
            #pragma unroll
            for (int i = 0; i < 4; i++)
                #pragma unroll
                for (int j = 0; j < 2; j++)
                    acc[i][j] = __builtin_amdgcn_mfma_f32_16x16x32_bf16(af[i], bfr[j], acc[i][j], 0, 0, 0);
        }
        __syncthreads();
    }

    #pragma unroll
    for (int j = 0; j < 2; j++) {
        int n = n0 + nw + j*16 + l15;
        float bn = bias[n];
        #pragma unroll
        for (int i = 0; i < 4; i++) {
            int mbase = m0 + i*16 + quad*4;
            #pragma unroll
            for (int r = 0; r < 4; r++)
                Out[(size_t)(mbase + r)*D_ + n] = acc[i][j][r] + bn;
        }
    }
}

// ---------------- fused attention v5: wave-autonomous, zero-barrier K-loop ----
// Each wave owns 32 q rows. K tile -> A-frags, Vt tile -> B-frags directly from
// global (coalesced 16B/lane). P relayout via 4KB per-wave private LDS
// (swizzled, lgkmcnt only). No __syncthreads in the main loop.
__global__ __launch_bounds__(256, 2) void k_attn(
    const bf16* __restrict__ Q, const bf16* __restrict__ K, const bf16* __restrict__ Vt,
    const float* __restrict__ mask, bf16* __restrict__ Ctx)
{
    const int bh = blockIdx.y;
    const int b = bh >> 4, h = bh & 15;
    const int t = threadIdx.x;
    const int w = t >> 6, lane = t & 63, quad = lane >> 4, l15 = lane & 15;
    const int q0 = blockIdx.x * 128 + w * 32;
    const int s7 = l15 & 7;

    __shared__ __align__(16) bf16 Pw[4][32*64];   // per-wave P buffer (4 KB each)
    __shared__ float lsw[4][32];

    // Q B-frags for this wave's 32 q rows (Q pre-scaled by 1/8)
    bf16x8 qf[2][2];
    {
        const bf16* Qb = Q + ((size_t)bh*S_ + q0)*HD_;
        #pragma unroll
        for (int nt = 0; nt < 2; nt++)
            #pragma unroll
            for (int ks = 0; ks < 2; ks++)
                qf[nt][ks] = *(const bf16x8*)&Qb[(size_t)(nt*16 + l15)*HD_ + ks*32 + quad*8];
    }

    const bf16* Kb = K + (size_t)bh*S_*HD_ + (size_t)l15*HD_ + quad*8;
    const bf16* Vb = Vt + (size_t)bh*HD_*S_ + (size_t)l15*S_ + quad*8;

    f32x4 cacc[2][4];
    #pragma unroll
    for (int i = 0; i < 2; i++)
        #pragma unroll
        for (int j = 0; j < 4; j++)
            cacc[i][j] = (f32x4){0.f,0.f,0.f,0.f};
    f32x2 lac[2] = {(f32x2){0.f,0.f}, (f32x2){0.f,0.f}};

    // preload tile 0 fragments
    bf16x8 ka[4][2], vb[4][2];
    #pragma unroll
    for (int mt = 0; mt < 4; mt++)
        #pragma unroll
        for (int ks = 0; ks < 2; ks++)
            ka[mt][ks] = *(const bf16x8*)&Kb[(size_t)(mt*16)*HD_ + ks*32];
    #pragma unroll
    for (int nt2 = 0; nt2 < 4; nt2++)
        #pragma unroll
        for (int ch = 0; ch < 2; ch++)
            vb[nt2][ch] = *(const bf16x8*)&Vb[(size_t)(nt2*16)*S_ + ch*32];

    for (int it = 0; it < S_/64; it++) {
        const int k0 = it*64;

        // mask (per-quad broadcast loads)
        float4 mk[4];
        #pragma unroll
        for (int mt = 0; mt < 4; mt++)
            mk[mt] = *(const float4*)&mask[(size_t)b*S_ + k0 + mt*16 + quad*4];

        // QK: S^T[k][q], k rows = 64 (4 mt), q = wave's 32 (2 nt)
        f32x4 st[4][2];
        #pragma unroll
        for (int mt = 0; mt < 4; mt++)
            #pragma unroll
            for (int nt = 0; nt < 2; nt++)
                st[mt][nt] = (f32x4){0.f,0.f,0.f,0.f};
        #pragma unroll
        for (int ks = 0; ks < 2; ks++)
            #pragma unroll
            for (int mt = 0; mt < 4; mt++)
                #pragma unroll
                for (int nt = 0; nt < 2; nt++)
                    st[mt][nt] = __builtin_amdgcn_mfma_f32_16x16x32_bf16(ka[mt][ks], qf[nt][ks], st[mt][nt], 0, 0, 0);

        // prefetch next K tile (regs free after QK; latency hidden by sigmoid+PV)
        if (it < S_/64 - 1) {
            #pragma unroll
            for (int mt = 0; mt < 4; mt++)
                #pragma unroll
                for (int ks = 0; ks < 2; ks++)
                    ka[mt][ks] = *(const bf16x8*)&Kb[(size_t)(k0 + 64 + mt*16)*HD_ + ks*32];
        }

        // packed-f32x2 sigmoid + pack to bf16 + per-wave LDS write (swizzled)
        #pragma unroll
        for (int mt = 0; mt < 4; mt++) {
            f32x2 mlo = {(1.0f - mk[mt].x)*-10000.0f, (1.0f - mk[mt].y)*-10000.0f};
            f32x2 mhi = {(1.0f - mk[mt].z)*-10000.0f, (1.0f - mk[mt].w)*-10000.0f};
            #pragma unroll
            for (int nt = 0; nt < 2; nt++) {
                f32x2 s0 = {st[mt][nt][0], st[mt][nt][1]};
                f32x2 s1 = {st[mt][nt][2], st[mt][nt][3]};
                s0 += mlo; s1 += mhi;
                s0 = __builtin_elementwise_min(__builtin_elementwise_max(s0, (f32x2)(-3.0f)), (f32x2)(3.0f));
                s1 = __builtin_elementwise_min(__builtin_elementwise_max(s1, (f32x2)(-3.0f)), (f32x2)(3.0f));
                f32x2 g0 = s0 * (s0*s0*(f32x2)(-0.01f) + (f32x2)(0.25f)) + (f32x2)(0.5f);
                f32x2 g1 = s1 * (s1*s1*(f32x2)(-0.01f) + (f32x2)(0.25f)) + (f32x2)(0.5f);
                g0 = __builtin_elementwise_min(__builtin_elementwise_max(g0, (f32x2)(0.01f)), (f32x2)(0.99f));
                g1 = __builtin_elementwise_min(__builtin_elementwise_max(g1, (f32x2)(0.01f)), (f32x2)(0.99f));
                lac[nt] += g0 + g1;
                union { bf16 h2[2]; uint32_t u; } p0, p1;
                p0.h2[0] = (bf16)g0.x; p0.h2[1] = (bf16)g0.y;
                p1.h2[0] = (bf16)g1.x; p1.h2[1] = (bf16)g1.y;
                uint2 pk = {p0.u, p1.u};
                int ql = nt*16 + l15;
                *(uint2*)&Pw[w][ql*64 + (((mt*2 + (quad>>1)) ^ s7)*8) + (quad&1)*4] = pk;
            }
        }

        // read P back as A-frags (same-wave dep -> lgkmcnt only, no barrier)
        bf16x8 pf[2][2];
        #pragma unroll
        for (int ch = 0; ch < 2; ch++)
            #pragma unroll
            for (int nt = 0; nt < 2; nt++)
                pf[ch][nt] = *(const bf16x8*)&Pw[w][(nt*16 + l15)*64 + (((ch*4 + quad) ^ s7)*8)];

        // PV: ctx[q][hd] += P[q][k] * V[k][hd]
        #pragma unroll
        for (int ch = 0; ch < 2; ch++)
            #pragma unroll
            for (int nt = 0; nt < 2; nt++)
                #pragma unroll
                for (int nt2 = 0; nt2 < 4; nt2++)
                    cacc[nt][nt2] = __builtin_amdgcn_mfma_f32_16x16x32_bf16(pf[ch][nt], vb[nt2][ch], cacc[nt][nt2], 0, 0, 0);

        // prefetch next V tile
        if (it < S_/64 - 1) {
            #pragma unroll
            for (int nt2 = 0; nt2 < 4; nt2++)
                #pragma unroll
                for (int ch = 0; ch < 2; ch++)
                    vb[nt2][ch] = *(const bf16x8*)&Vb[(size_t)(nt2*16)*S_ + k0 + 64 + ch*32];
        }
    }

    // row-sum: reduce across quads (k was spread over quads+mt), per-wave LDS
    #pragma unroll
    for (int nt = 0; nt < 2; nt++) {
        float v = lac[nt].x + lac[nt].y;
        v += __shfl_xor(v, 16);
        v += __shfl_xor(v, 32);
        if (quad == 0) lsw[w][nt*16 + l15] = v;
    }
    f32x4 s4[2];
    #pragma unroll
    for (int nt = 0; nt < 2; nt++)
        s4[nt] = *(const f32x4*)&lsw[w][nt*16 + quad*4];

    // normalize + store ctx
    #pragma unroll
    for (int nt = 0; nt < 2; nt++) {
        #pragma unroll
        for (int r = 0; r < 4; r++) {
            float rinv = 1.0f / (s4[nt][r] + 1e-8f);
            size_t row = (size_t)(b*S_ + q0 + nt*16 + quad*4 + r);
            #pragma unroll
            for (int nt2 = 0; nt2 < 4; nt2++)
                Ctx[row*D_ + h*HD_ + nt2*16 + l15] = (bf16)(cacc[nt][nt2][r] * rinv);
        }
    }
}

extern "C" void kernel_launch(void* const* d_in, const int* in_sizes, int n_in,
                              void* d_out, int out_size, void* d_ws, size_t ws_size,
                              hipStream_t stream) {
    const float* hs   = (const float*)d_in[0];
    const float* mask = (const float*)d_in[1];
    const float* Wq   = (const float*)d_in[2];
    const float* bq   = (const float*)d_in[3];
    const float* Wk   = (const float*)d_in[4];
    const float* bk   = (const float*)d_in[5];
    const float* Wv   = (const float*)d_in[6];
    const float* bv   = (const float*)d_in[7];
    const float* Wo   = (const float*)d_in[8];
    const float* bo   = (const float*)d_in[9];
    float* out = (float*)d_out;

    char* ws = (char*)d_ws;
    const size_t MB = 1024*1024;
    bf16* hb   = (bf16*)(ws);            // [M_,D_]        8 MB
    bf16* wqb  = (bf16*)(ws + 8*MB);     // [D_,D_]        2 MB
    bf16* wkb  = (bf16*)(ws + 10*MB);
    bf16* wvb  = (bf16*)(ws + 12*MB);
    bf16* wob  = (bf16*)(ws + 14*MB);
    bf16* qb   = (bf16*)(ws + 16*MB);    // [BH][S][HD]    8 MB
    bf16* kb   = (bf16*)(ws + 24*MB);    // [BH][S][HD]    8 MB
    bf16* vtb  = (bf16*)(ws + 32*MB);    // [BH][HD][S]    8 MB
    bf16* ctxb = (bf16*)(ws + 40*MB);    // [M_,D_]        8 MB

    k_cvt_all<<<2048 + 4*512, 256, 0, stream>>>(hs, Wq, Wk, Wv, Wo, hb, wqb, wkb, wvb, wob);

    k_gemm_qkv<<<dim3(D_/128, M_/128, 3), 256, 0, stream>>>(
        hb, wqb, wkb, wvb, bq, bk, bv, qb, kb, vtb);

    k_attn<<<dim3(S_/128, B_*H_), 256, 0, stream>>>(qb, kb, vtb, mask, ctxb);

    k_gemm_out<<<dim3(D_/128, M_/64), 256, 0, stream>>>(ctxb, wob, bo, out);
}

// Round 6
// 272.347 us; speedup vs baseline: 1.0237x; 1.0237x over previous
//
#include <hip/hip_runtime.h>
#include <stdint.h>

#define B_ 2
#define S_ 2048
#define D_ 1024
#define H_ 16
#define HD_ 64
#define M_ (B_*S_)   // 4096

typedef __bf16 bf16;
typedef __attribute__((ext_vector_type(8))) __bf16 bf16x8;
typedef __attribute__((ext_vector_type(4))) float f32x4;

// async global->LDS, 16B per lane. LDS dest = uniform base + lane*16.
__device__ __forceinline__ void gload16(const bf16* g, bf16* l) {
    __builtin_amdgcn_global_load_lds(
        (const __attribute__((address_space(1))) void*)g,
        (__attribute__((address_space(3))) void*)l, 16, 0, 0);
}

// ---------------- fp32 -> bf16 converts (single launch) ----------------
__global__ void k_cvt_all(const float* __restrict__ hs,
                          const float* __restrict__ Wq, const float* __restrict__ Wk,
                          const float* __restrict__ Wv, const float* __restrict__ Wo,
                          bf16* __restrict__ hb,
                          bf16* __restrict__ wqb, bf16* __restrict__ wkb,
                          bf16* __restrict__ wvb, bf16* __restrict__ wob) {
    int blk = blockIdx.x;
    const float* s; bf16* d; int base;
    if (blk < 2048) { s = hs; d = hb; base = blk; }
    else {
        int r = blk - 2048; int which = r >> 9; base = r & 511;
        s = (which==0)?Wq:(which==1)?Wk:(which==2)?Wv:Wo;
        d = (which==0)?wqb:(which==1)?wkb:(which==2)?wvb:wob;
    }
    int idx = base*2048 + threadIdx.x*8;
    float4 a = *(const float4*)(s + idx);
    float4 b = *(const float4*)(s + idx + 4);
    bf16 o[8] = {(bf16)a.x,(bf16)a.y,(bf16)a.z,(bf16)a.w,
                 (bf16)b.x,(bf16)b.y,(bf16)b.z,(bf16)b.w};
    *(int4*)(d + idx) = *(const int4*)o;
}

// ---------------- QKV projection GEMM (coalesced LDS-transpose epilogue) ----
// z=0: Q -> [BH][S][HD] scaled 1/8 ; z=1: K -> [BH][S][HD] ; z=2: V -> [BH][HD][S]
__global__ __launch_bounds__(256) void k_gemm_qkv(
    const bf16* __restrict__ X,
    const bf16* __restrict__ Wq, const bf16* __restrict__ Wk, const bf16* __restrict__ Wv,
    const float* __restrict__ bq, const float* __restrict__ bk, const float* __restrict__ bv,
    bf16* __restrict__ Qo, bf16* __restrict__ Ko, bf16* __restrict__ Vo)
{
    const int z = blockIdx.z;
    const bf16* W = (z==0) ? Wq : (z==1) ? Wk : Wv;
    const float* bias = (z==0) ? bq : (z==1) ? bk : bv;
    const int n0 = blockIdx.x * 128;
    const int m0 = blockIdx.y * 128;
    const int t = threadIdx.x;
    const int w = t >> 6, lane = t & 63, quad = lane >> 4, l15 = lane & 15;
    const int lr = lane >> 3;
    const int lc = (lane & 7) ^ lr;
    const int sx = l15 & 7;
    const int mw = (w >> 1) * 64, nw = (w & 1) * 64;

    __shared__ __align__(16) char smraw[128*136*2];  // 34816 B, aliased
    bf16* As  = (bf16*)smraw;               // [128][64]
    bf16* Bs  = (bf16*)(smraw + 16384);     // [128][64]
    bf16* epi = (bf16*)smraw;               // [128][136]

    f32x4 acc[4][4];
    #pragma unroll
    for (int i = 0; i < 4; i++)
        #pragma unroll
        for (int j = 0; j < 4; j++)
            acc[i][j] = (f32x4){0.f,0.f,0.f,0.f};

    const bf16* gA = X + (size_t)(m0 + w*8 + lr)*D_ + lc*8;
    const bf16* gB = W + (size_t)(n0 + w*8 + lr)*D_ + lc*8;

    for (int k0 = 0; k0 < D_; k0 += 64) {
        #pragma unroll
        for (int c = 0; c < 4; c++) {
            gload16(gA + (size_t)c*32*D_ + k0, &As[c*2048 + w*512]);
            gload16(gB + (size_t)c*32*D_ + k0, &Bs[c*2048 + w*512]);
        }
        __syncthreads();
        #pragma unroll
        for (int ks = 0; ks < 2; ks++) {
            bf16x8 af[4], bfr[4];
            #pragma unroll
            for (int i = 0; i < 4; i++)
                af[i] = *(const bf16x8*)&As[(mw + i*16 + l15)*64 + (((ks*4+quad)^sx)*8)];
            #pragma unroll
            for (int j = 0; j < 4; j++)
                bfr[j] = *(const bf16x8*)&Bs[(nw + j*16 + l15)*64 + (((ks*4+quad)^sx)*8)];
            #pragma unroll
            for (int i = 0; i < 4; i++)
                #pragma unroll
                for (int j = 0; j < 4; j++)
                    acc[i][j] = __builtin_amdgcn_mfma_f32_16x16x32_bf16(af[i], bfr[j], acc[i][j], 0, 0, 0);
        }
        __syncthreads();
    }

    // ---- epilogue: acc -> LDS (transposed layouts) -> coalesced global ----
    const float scale = (z == 0) ? 0.125f : 1.0f;
    if (z == 2) {
        #pragma unroll
        for (int j = 0; j < 4; j++) {
            int n = nw + j*16 + l15;
            float bn = bias[n0 + n];
            #pragma unroll
            for (int i = 0; i < 4; i++) {
                int mloc = mw + i*16 + quad*4;
                union { bf16 h4[4]; uint2 u; } pk;
                #pragma unroll
                for (int r = 0; r < 4; r++) pk.h4[r] = (bf16)(acc[i][j][r] + bn);
                *(uint2*)&epi[n*136 + mloc] = pk.u;
            }
        }
    } else {
        #pragma unroll
        for (int j = 0; j < 4; j++) {
            int n = nw + j*16 + l15;
            float bn = bias[n0 + n];
            #pragma unroll
            for (int i = 0; i < 4; i++) {
                int mloc = mw + i*16 + quad*4;
                #pragma unroll
                for (int r = 0; r < 4; r++)
                    epi[(mloc + r)*136 + n] = (bf16)((acc[i][j][r] + bn) * scale);
            }
        }
    }
    __syncthreads();
    if (z == 2) {
        #pragma unroll
        for (int kk = 0; kk < 8; kk++) {
            int c = t + 256*kk;
            int row = c >> 4;             // local n (dim)
            int mcol = (c & 15) * 8;      // local m (token)
            int4 val = *(const int4*)&epi[row*136 + mcol];
            int n = n0 + row; int hh = n >> 6, hd = n & 63;
            int m = m0 + mcol; int bb = m >> 11, s = m & 2047;
            *(int4*)&Vo[((size_t)((bb*H_ + hh)*HD_ + hd))*S_ + s] = val;
        }
    } else {
        bf16* Out = (z == 0) ? Qo : Ko;
        #pragma unroll
        for (int kk = 0; kk < 8; kk++) {
            int c = t + 256*kk;
            int row = c >> 4;             // local m (token)
            int ncol = (c & 15) * 8;      // local n (dim)
            int4 val = *(const int4*)&epi[row*136 + ncol];
            int m = m0 + row; int bb = m >> 11, s = m & 2047;
            int n = n0 + ncol; int hh = n >> 6, hd = n & 63;
            *(int4*)&Out[((size_t)((bb*H_ + hh)*S_ + s))*HD_ + hd] = val;
        }
    }
}

// ---------------- output projection GEMM (64x128 tile) -------------------
// A = normalize(P0 + P1) fused during staging (bf16 partials, per-head lsum)
__global__ __launch_bounds__(256) void k_gemm_out(
    const bf16* __restrict__ P0, const bf16* __restrict__ P1,
    const float* __restrict__ L0, const float* __restrict__ L1,
    const bf16* __restrict__ W,
    const float* __restrict__ bias, float* __restrict__ Out)
{
    const int n0 = blockIdx.x * 128;
    const int m0 = blockIdx.y * 64;
    const int t = threadIdx.x;
    const int w = t >> 6, lane = t & 63, quad = lane >> 4, l15 = lane & 15;
    const int lr = lane >> 3;
    const int lc = (lane & 7) ^ lr;
    const int sx = l15 & 7;
    const int nw = w * 32;

    __shared__ __align__(16) bf16 As[64*64];
    __shared__ __align__(16) bf16 Bs[128*64];

    f32x4 acc[4][2];
    #pragma unroll
    for (int i = 0; i < 4; i++)
        #pragma unroll
        for (int j = 0; j < 2; j++)
            acc[i][j] = (f32x4){0.f,0.f,0.f,0.f};

    const bf16* gB = W + (size_t)(n0 + w*8 + lr)*D_ + lc*8;

    for (int k0 = 0; k0 < D_; k0 += 64) {
        const int head = k0 >> 6;
        // A staging: combine partials + normalize + pack -> LDS (same layout as DMA)
        #pragma unroll
        for (int c = 0; c < 2; c++) {
            int row = m0 + c*32 + w*8 + lr;
            int bb = row >> 11, s = row & 2047;
            int lidx = (bb*H_ + head)*S_ + s;
            float l = L0[lidx] + L1[lidx];
            float inv = 1.0f / (l + 1e-8f);
            size_t gofs = (size_t)row*D_ + k0 + lc*8;
            bf16x8 a0 = *(const bf16x8*)&P0[gofs];
            bf16x8 a1 = *(const bf16x8*)&P1[gofs];
            bf16 o8[8];
            #pragma unroll
            for (int r = 0; r < 8; r++)
                o8[r] = (bf16)(((float)a0[r] + (float)a1[r]) * inv);
            *(int4*)&As[c*2048 + w*512 + lane*8] = *(const int4*)o8;
        }
        // B staging: DMA
        #pragma unroll
        for (int c = 0; c < 4; c++)
            gload16(gB + (size_t)c*32*D_ + k0, &Bs[c*2048 + w*512]);
        __syncthreads();
        #pragma unroll
        for (int ks = 0; ks < 2; ks++) {
            bf16x8 af[4], bfr[2];
            #pragma unroll
            for (int i = 0; i < 4; i++)
                af[i] = *(const bf16x8*)&As[(i*16 + l15)*64 + (((ks*4+quad)^sx)*8)];
            #pragma unroll
            for (int j = 0; j < 2; j++)
                bfr[j] = *(const bf16x8*)&Bs[(nw + j*16 + l15)*64 + (((ks*4+quad)^sx)*8)];
            #pragma unroll
            for (int i = 0; i < 4; i++)
                #pragma unroll
                for (int j = 0; j < 2; j++)
                    acc[i][j] = __builtin_amdgcn_mfma_f32_16x16x32_bf16(af[i], bfr[j], acc[i][j], 0, 0, 0);
        }
        __syncthreads();
    }

    #pragma unroll
    for (int j = 0; j < 2; j++) {
        int n = n0 + nw + j*16 + l15;
        float bn = bias[n];
        #pragma unroll
        for (int i = 0; i < 4; i++) {
            int mbase = m0 + i*16 + quad*4;
            #pragma unroll
            for (int r = 0; r < 4; r++)
                Out[(size_t)(mbase + r)*D_ + n] = acc[i][j][r] + bn;
        }
    }
}

// ---------------- fused attention v6: R3 structure + K-range split (z) ------
// grid (16, 32, 2): z selects k-half [z*1024, z*1024+1024). Each block writes
// UNNORMALIZED bf16 partial ctx + per-(bh,q) partial row-sum. Combine happens
// in k_gemm_out staging (sums are linear -- no softmax rescaling needed).
__global__ __launch_bounds__(256) void k_attn(
    const bf16* __restrict__ Q, const bf16* __restrict__ K, const bf16* __restrict__ Vt,
    const float* __restrict__ mask,
    bf16* __restrict__ P0, bf16* __restrict__ P1,
    float* __restrict__ L0, float* __restrict__ L1)
{
    const int bh = blockIdx.y;
    const int b = bh >> 4, h = bh & 15;
    const int q0 = blockIdx.x * 128;
    const int z = blockIdx.z;
    bf16* __restrict__ Po = z ? P1 : P0;
    float* __restrict__ Lo = z ? L1 : L0;
    const int t = threadIdx.x;
    const int w = t >> 6, lane = t & 63, quad = lane >> 4, l15 = lane & 15;
    const int lr = lane >> 3;
    const int lc = (lane & 7) ^ lr;
    const int sx = l15 & 7;

    __shared__ __align__(16) bf16 Ks[2][64*64];
    __shared__ __align__(16) bf16 Vs[2][64*64];
    __shared__ __align__(16) bf16 Ps[128*64];   // P[q][k], xor-swizzled rows
    __shared__ float lsumP[4][128];

    // Q fragments in registers: all 128 q rows (B-operand), 16 frags
    bf16x8 qf[8][2];
    const bf16* Qbase = Q + ((size_t)bh*S_ + q0)*HD_;
    #pragma unroll
    for (int qs = 0; qs < 8; qs++)
        #pragma unroll
        for (int ks = 0; ks < 2; ks++)
            qf[qs][ks] = *(const bf16x8*)&Qbase[(size_t)(qs*16 + l15)*HD_ + ks*32 + quad*8];

    f32x4 cacc[2][4];
    #pragma unroll
    for (int i = 0; i < 2; i++)
        #pragma unroll
        for (int j = 0; j < 4; j++)
            cacc[i][j] = (f32x4){0.f,0.f,0.f,0.f};
    float lac[8];
    #pragma unroll
    for (int qs = 0; qs < 8; qs++) lac[qs] = 0.f;

    const int kb0 = z * (S_/2);   // this block's k-range base
    const bf16* Kst = K + ((size_t)bh*S_ + w*8 + lr)*HD_ + lc*8;
    const bf16* Vst = Vt + ((size_t)bh*HD_ + w*8 + lr)*S_ + lc*8;

    // prologue: stage tile 0 of this half
    #pragma unroll
    for (int c = 0; c < 2; c++)
        gload16(Kst + (size_t)(kb0 + c*32)*HD_, &Ks[0][c*2048 + w*512]);
    #pragma unroll
    for (int c = 0; c < 2; c++)
        gload16(Vst + (size_t)c*32*S_ + kb0, &Vs[0][c*2048 + w*512]);
    __syncthreads();

    for (int it = 0; it < S_/128; it++) {   // 16 iters over this half
        const int cur = it & 1;
        const int k0 = kb0 + it*64;

        // QK: S^T rows k in [w*16, w*16+16), all 128 q
        f32x4 st[8];
        #pragma unroll
        for (int qs = 0; qs < 8; qs++) st[qs] = (f32x4){0.f,0.f,0.f,0.f};
        #pragma unroll
        for (int ks = 0; ks < 2; ks++) {
            bf16x8 af = *(const bf16x8*)&Ks[cur][(w*16 + l15)*64 + (((ks*4+quad)^sx)*8)];
            #pragma unroll
            for (int qs = 0; qs < 8; qs++)
                st[qs] = __builtin_amdgcn_mfma_f32_16x16x32_bf16(af, qf[qs][ks], st[qs], 0, 0, 0);
        }

        // mask + polynomial sigmoid + P write (k = k0 + w*16 + quad*4 + r)
        float4 m4 = *(const float4*)&mask[(size_t)b*S_ + k0 + w*16 + quad*4];
        float mv[4] = {(1.0f-m4.x)*-10000.0f, (1.0f-m4.y)*-10000.0f,
                       (1.0f-m4.z)*-10000.0f, (1.0f-m4.w)*-10000.0f};
        const int c8 = (w*2 + (quad>>1)) ^ sx;
        #pragma unroll
        for (int qs = 0; qs < 8; qs++) {
            union { bf16 h4[4]; uint2 u; } pk;
            #pragma unroll
            for (int r = 0; r < 4; r++) {
                float s = st[qs][r] + mv[r];
                float c = __builtin_amdgcn_fmed3f(s, -3.0f, 3.0f);
                float u = fmaf(c*c, -0.01f, 0.25f);
                float sg = fmaf(c, u, 0.5f);
                sg = __builtin_amdgcn_fmed3f(sg, 0.01f, 0.99f);
                lac[qs] += sg;
                pk.h4[r] = (bf16)sg;
            }
            *(uint2*)&Ps[(qs*16 + l15)*64 + c8*8 + (quad&1)*4] = pk.u;
        }
        __syncthreads();   // B1: P visible to all; K-frag reads done

        // prefetch next K/V tile into other buffer
        if (it < S_/128 - 1) {
            const int k1 = k0 + 64;
            #pragma unroll
            for (int c = 0; c < 2; c++)
                gload16(Kst + (size_t)(k1 + c*32)*HD_, &Ks[cur^1][c*2048 + w*512]);
            #pragma unroll
            for (int c = 0; c < 2; c++)
                gload16(Vst + (size_t)c*32*S_ + k1, &Vs[cur^1][c*2048 + w*512]);
        }

        // PV: wave owns q in [w*32, w*32+32)
        #pragma unroll
        for (int ks = 0; ks < 2; ks++) {
            bf16x8 pf[2], vf[4];
            #pragma unroll
            for (int m2 = 0; m2 < 2; m2++)
                pf[m2] = *(const bf16x8*)&Ps[(w*32 + m2*16 + l15)*64 + (((ks*4+quad)^sx)*8)];
            #pragma unroll
            for (int nt = 0; nt < 4; nt++)
                vf[nt] = *(const bf16x8*)&Vs[cur][(nt*16 + l15)*64 + (((ks*4+quad)^sx)*8)];
            #pragma unroll
            for (int m2 = 0; m2 < 2; m2++)
                #pragma unroll
                for (int nt = 0; nt < 4; nt++)
                    cacc[m2][nt] = __builtin_amdgcn_mfma_f32_16x16x32_bf16(pf[m2], vf[nt], cacc[m2][nt], 0, 0, 0);
        }
        __syncthreads();   // B2: DMA drained; PV reads done
    }

    // cross-wave row-sum reduce (each wave holds partial over its k subset)
    #pragma unroll
    for (int qs = 0; qs < 8; qs++) {
        float v = lac[qs];
        v += __shfl_xor(v, 16);
        v += __shfl_xor(v, 32);
        if (quad == 0) lsumP[w][qs*16 + l15] = v;
    }
    __syncthreads();

    // store UNNORMALIZED partial ctx + partial row-sums
    #pragma unroll
    for (int m2 = 0; m2 < 2; m2++) {
        #pragma unroll
        for (int r = 0; r < 4; r++) {
            int q = w*32 + m2*16 + quad*4 + r;
            float s = lsumP[0][q] + lsumP[1][q] + lsumP[2][q] + lsumP[3][q];
            if (l15 == 0)
                Lo[(size_t)bh*S_ + q0 + q] = s;
            size_t row = (size_t)(b*S_ + q0 + q);
            #pragma unroll
            for (int nt = 0; nt < 4; nt++)
                Po[row*D_ + h*HD_ + nt*16 + l15] = (bf16)cacc[m2][nt][r];
        }
    }
}

extern "C" void kernel_launch(void* const* d_in, const int* in_sizes, int n_in,
                              void* d_out, int out_size, void* d_ws, size_t ws_size,
                              hipStream_t stream) {
    const float* hs   = (const float*)d_in[0];
    const float* mask = (const float*)d_in[1];
    const float* Wq   = (const float*)d_in[2];
    const float* bq   = (const float*)d_in[3];
    const float* Wk   = (const float*)d_in[4];
    const float* bk   = (const float*)d_in[5];
    const float* Wv   = (const float*)d_in[6];
    const float* bv   = (const float*)d_in[7];
    const float* Wo   = (const float*)d_in[8];
    const float* bo   = (const float*)d_in[9];
    float* out = (float*)d_out;

    char* ws = (char*)d_ws;
    const size_t MB = 1024*1024;
    bf16*  hb   = (bf16*)(ws);            // [M_,D_] 8 MB  (freed after qkv -> P1)
    bf16*  P1   = (bf16*)(ws);            // partial ctx z=1 (aliases hb)
    bf16*  wqb  = (bf16*)(ws + 8*MB);     // 2 MB (freed after qkv -> L0/L1)
    float* L0   = (float*)(ws + 8*MB);            // 256 KB
    float* L1   = (float*)(ws + 8*MB + 512*1024); // 256 KB
    bf16*  wkb  = (bf16*)(ws + 10*MB);
    bf16*  wvb  = (bf16*)(ws + 12*MB);
    bf16*  wob  = (bf16*)(ws + 14*MB);
    bf16*  qb   = (bf16*)(ws + 16*MB);    // [BH][S][HD]    8 MB
    bf16*  kb   = (bf16*)(ws + 24*MB);    // [BH][S][HD]    8 MB
    bf16*  vtb  = (bf16*)(ws + 32*MB);    // [BH][HD][S]    8 MB
    bf16*  P0   = (bf16*)(ws + 40*MB);    // partial ctx z=0, 8 MB

    k_cvt_all<<<2048 + 4*512, 256, 0, stream>>>(hs, Wq, Wk, Wv, Wo, hb, wqb, wkb, wvb, wob);

    k_gemm_qkv<<<dim3(D_/128, M_/128, 3), 256, 0, stream>>>(
        hb, wqb, wkb, wvb, bq, bk, bv, qb, kb, vtb);

    k_attn<<<dim3(S_/128, B_*H_, 2), 256, 0, stream>>>(qb, kb, vtb, mask, P0, P1, L0, L1);

    k_gemm_out<<<dim3(D_/128, M_/64), 256, 0, stream>>>(P0, P1, L0, L1, wob, bo, out);
}

// Round 7
// 239.411 us; speedup vs baseline: 1.1645x; 1.1376x over previous
//
#include <hip/hip_runtime.h>
#include <stdint.h>

#define B_ 2
#define S_ 2048
#define D_ 1024
#define H_ 16
#define HD_ 64
#define M_ (B_*S_)   // 4096

typedef __bf16 bf16;
typedef __attribute__((ext_vector_type(8))) __bf16 bf16x8;
typedef __attribute__((ext_vector_type(4))) float f32x4;

// async global->LDS, 16B per lane. LDS dest = uniform base + lane*16.
__device__ __forceinline__ void gload16(const bf16* g, bf16* l) {
    __builtin_amdgcn_global_load_lds(
        (const __attribute__((address_space(1))) void*)g,
        (__attribute__((address_space(3))) void*)l, 16, 0, 0);
}

// ---------------- fp32 -> bf16 converts (single launch) ----------------
__global__ void k_cvt_all(const float* __restrict__ hs,
                          const float* __restrict__ Wq, const float* __restrict__ Wk,
                          const float* __restrict__ Wv, const float* __restrict__ Wo,
                          bf16* __restrict__ hb,
                          bf16* __restrict__ wqb, bf16* __restrict__ wkb,
                          bf16* __restrict__ wvb, bf16* __restrict__ wob) {
    int blk = blockIdx.x;
    const float* s; bf16* d; int base;
    if (blk < 2048) { s = hs; d = hb; base = blk; }
    else {
        int r = blk - 2048; int which = r >> 9; base = r & 511;
        s = (which==0)?Wq:(which==1)?Wk:(which==2)?Wv:Wo;
        d = (which==0)?wqb:(which==1)?wkb:(which==2)?wvb:wob;
    }
    int idx = base*2048 + threadIdx.x*8;
    float4 a = *(const float4*)(s + idx);
    float4 b = *(const float4*)(s + idx + 4);
    bf16 o[8] = {(bf16)a.x,(bf16)a.y,(bf16)a.z,(bf16)a.w,
                 (bf16)b.x,(bf16)b.y,(bf16)b.z,(bf16)b.w};
    *(int4*)(d + idx) = *(const int4*)o;
}

// ---------------- QKV projection GEMM (coalesced LDS-transpose epilogue) ----
// z=0: Q -> [BH][S][HD] scaled 1/8 ; z=1: K -> [BH][S][HD] ; z=2: V -> [BH][HD][S]
__global__ __launch_bounds__(256) void k_gemm_qkv(
    const bf16* __restrict__ X,
    const bf16* __restrict__ Wq, const bf16* __restrict__ Wk, const bf16* __restrict__ Wv,
    const float* __restrict__ bq, const float* __restrict__ bk, const float* __restrict__ bv,
    bf16* __restrict__ Qo, bf16* __restrict__ Ko, bf16* __restrict__ Vo)
{
    const int z = blockIdx.z;
    const bf16* W = (z==0) ? Wq : (z==1) ? Wk : Wv;
    const float* bias = (z==0) ? bq : (z==1) ? bk : bv;
    const int n0 = blockIdx.x * 128;
    const int m0 = blockIdx.y * 128;
    const int t = threadIdx.x;
    const int w = t >> 6, lane = t & 63, quad = lane >> 4, l15 = lane & 15;
    const int lr = lane >> 3;
    const int lc = (lane & 7) ^ lr;
    const int sx = l15 & 7;
    const int mw = (w >> 1) * 64, nw = (w & 1) * 64;

    __shared__ __align__(16) char smraw[128*136*2];  // 34816 B, aliased
    bf16* As  = (bf16*)smraw;               // [128][64]
    bf16* Bs  = (bf16*)(smraw + 16384);     // [128][64]
    bf16* epi = (bf16*)smraw;               // [128][136]

    f32x4 acc[4][4];
    #pragma unroll
    for (int i = 0; i < 4; i++)
        #pragma unroll
        for (int j = 0; j < 4; j++)
            acc[i][j] = (f32x4){0.f,0.f,0.f,0.f};

    const bf16* gA = X + (size_t)(m0 + w*8 + lr)*D_ + lc*8;
    const bf16* gB = W + (size_t)(n0 + w*8 + lr)*D_ + lc*8;

    for (int k0 = 0; k0 < D_; k0 += 64) {
        #pragma unroll
        for (int c = 0; c < 4; c++) {
            gload16(gA + (size_t)c*32*D_ + k0, &As[c*2048 + w*512]);
            gload16(gB + (size_t)c*32*D_ + k0, &Bs[c*2048 + w*512]);
        }
        __syncthreads();
        #pragma unroll
        for (int ks = 0; ks < 2; ks++) {
            bf16x8 af[4], bfr[4];
            #pragma unroll
            for (int i = 0; i < 4; i++)
                af[i] = *(const bf16x8*)&As[(mw + i*16 + l15)*64 + (((ks*4+quad)^sx)*8)];
            #pragma unroll
            for (int j = 0; j < 4; j++)
                bfr[j] = *(const bf16x8*)&Bs[(nw + j*16 + l15)*64 + (((ks*4+quad)^sx)*8)];
            #pragma unroll
            for (int i = 0; i < 4; i++)
                #pragma unroll
                for (int j = 0; j < 4; j++)
                    acc[i][j] = __builtin_amdgcn_mfma_f32_16x16x32_bf16(af[i], bfr[j], acc[i][j], 0, 0, 0);
        }
        __syncthreads();
    }

    // ---- epilogue: acc -> LDS (transposed layouts) -> coalesced global ----
    const float scale = (z == 0) ? 0.125f : 1.0f;
    if (z == 2) {
        #pragma unroll
        for (int j = 0; j < 4; j++) {
            int n = nw + j*16 + l15;
            float bn = bias[n0 + n];
            #pragma unroll
            for (int i = 0; i < 4; i++) {
                int mloc = mw + i*16 + quad*4;
                union { bf16 h4[4]; uint2 u; } pk;
                #pragma unroll
                for (int r = 0; r < 4; r++) pk.h4[r] = (bf16)(acc[i][j][r] + bn);
                *(uint2*)&epi[n*136 + mloc] = pk.u;
            }
        }
    } else {
        #pragma unroll
        for (int j = 0; j < 4; j++) {
            int n = nw + j*16 + l15;
            float bn = bias[n0 + n];
            #pragma unroll
            for (int i = 0; i < 4; i++) {
                int mloc = mw + i*16 + quad*4;
                #pragma unroll
                for (int r = 0; r < 4; r++)
                    epi[(mloc + r)*136 + n] = (bf16)((acc[i][j][r] + bn) * scale);
            }
        }
    }
    __syncthreads();
    if (z == 2) {
        #pragma unroll
        for (int kk = 0; kk < 8; kk++) {
            int c = t + 256*kk;
            int row = c >> 4;             // local n (dim)
            int mcol = (c & 15) * 8;      // local m (token)
            int4 val = *(const int4*)&epi[row*136 + mcol];
            int n = n0 + row; int hh = n >> 6, hd = n & 63;
            int m = m0 + mcol; int bb = m >> 11, s = m & 2047;
            *(int4*)&Vo[((size_t)((bb*H_ + hh)*HD_ + hd))*S_ + s] = val;
        }
    } else {
        bf16* Out = (z == 0) ? Qo : Ko;
        #pragma unroll
        for (int kk = 0; kk < 8; kk++) {
            int c = t + 256*kk;
            int row = c >> 4;             // local m (token)
            int ncol = (c & 15) * 8;      // local n (dim)
            int4 val = *(const int4*)&epi[row*136 + ncol];
            int m = m0 + row; int bb = m >> 11, s = m & 2047;
            int n = n0 + ncol; int hh = n >> 6, hd = n & 63;
            *(int4*)&Out[((size_t)((bb*H_ + hh)*S_ + s))*HD_ + hd] = val;
        }
    }
}

// ---------------- output projection GEMM (64x128 tile) ----------------
__global__ __launch_bounds__(256) void k_gemm_out(
    const bf16* __restrict__ X, const bf16* __restrict__ W,
    const float* __restrict__ bias, float* __restrict__ Out)
{
    const int n0 = blockIdx.x * 128;
    const int m0 = blockIdx.y * 64;
    const int t = threadIdx.x;
    const int w = t >> 6, lane = t & 63, quad = lane >> 4, l15 = lane & 15;
    const int lr = lane >> 3;
    const int lc = (lane & 7) ^ lr;
    const int sx = l15 & 7;
    const int nw = w * 32;

    __shared__ __align__(16) bf16 As[64*64];
    __shared__ __align__(16) bf16 Bs[128*64];

    f32x4 acc[4][2];
    #pragma unroll
    for (int i = 0; i < 4; i++)
        #pragma unroll
        for (int j = 0; j < 2; j++)
            acc[i][j] = (f32x4){0.f,0.f,0.f,0.f};

    const bf16* gA = X + (size_t)(m0 + w*8 + lr)*D_ + lc*8;
    const bf16* gB = W + (size_t)(n0 + w*8 + lr)*D_ + lc*8;

    for (int k0 = 0; k0 < D_; k0 += 64) {
        #pragma unroll
        for (int c = 0; c < 2; c++)
            gload16(gA + (size_t)c*32*D_ + k0, &As[c*2048 + w*512]);
        #pragma unroll
        for (int c = 0; c < 4; c++)
            gload16(gB + (size_t)c*32*D_ + k0, &Bs[c*2048 + w*512]);
        __syncthreads();
        #pragma unroll
        for (int ks = 0; ks < 2; ks++) {
            bf16x8 af[4], bfr[2];
            #pragma unroll
            for (int i = 0; i < 4; i++)
                af[i] = *(const bf16x8*)&As[(i*16 + l15)*64 + (((ks*4+quad)^sx)*8)];
            #pragma unroll
            for (int j = 0; j < 2; j++)
                bfr[j] = *(const bf16x8*)&Bs[(nw + j*16 + l15)*64 + (((ks*4+quad)^sx)*8)];
            #pragma unroll
            for (int i = 0; i < 4; i++)
                #pragma unroll
                for (int j = 0; j < 2; j++)
                    acc[i][j] = __builtin_amdgcn_mfma_f32_16x16x32_bf16(af[i], bfr[j], acc[i][j], 0, 0, 0);
        }
        __syncthreads();
    }

    #pragma unroll
    for (int j = 0; j < 2; j++) {
        int n = n0 + nw + j*16 + l15;
        float bn = bias[n];
        #pragma unroll
        for (int i = 0; i < 4; i++) {
            int mbase = m0 + i*16 + quad*4;
            #pragma unroll
            for (int r = 0; r < 4; r++)
                Out[(size_t)(mbase + r)*D_ + n] = acc[i][j][r] + bn;
        }
    }
}

// ---------------- fused attention v7: q64 tile + k-split QK, 33 KB LDS -------
// grid (32, 32) = 1024 blocks -> 4 blocks/CU. Wave owns k in [w*16,w*16+16) for
// QK (all 64 q in regs) and q in [w*16,w*16+16) for PV. K dbuf, V single buf,
// P single buf. 2 barriers/iter. DMA issued at loop top:
//   V(it)->Vs   (safe: B2(it-1) cleared PV(it-1) readers; drained at B1(it))
//   K(it+1)->Ks[cur^1] (safe: B2(it-1) cleared QK(it-1) readers)
__global__ __launch_bounds__(256) void k_attn(
    const bf16* __restrict__ Q, const bf16* __restrict__ K, const bf16* __restrict__ Vt,
    const float* __restrict__ mask, bf16* __restrict__ Ctx)
{
    const int bh = blockIdx.y;
    const int b = bh >> 4, h = bh & 15;
    const int q0 = blockIdx.x * 64;
    const int t = threadIdx.x;
    const int w = t >> 6, lane = t & 63, quad = lane >> 4, l15 = lane & 15;
    const int lr = lane >> 3;
    const int lc = (lane & 7) ^ lr;
    const int sx = l15 & 7;

    __shared__ __align__(16) bf16 Ks[2][64*64];   // 16 KB
    __shared__ __align__(16) bf16 Vs[64*64];      // 8 KB
    __shared__ __align__(16) bf16 Ps[64*64];      // 8 KB, xor-swizzled rows
    __shared__ float lsumP[4][64];

    // Q fragments in registers: all 64 q rows (B-operand), 8 frags
    bf16x8 qf[4][2];
    const bf16* Qbase = Q + ((size_t)bh*S_ + q0)*HD_;
    #pragma unroll
    for (int qs = 0; qs < 4; qs++)
        #pragma unroll
        for (int ks = 0; ks < 2; ks++)
            qf[qs][ks] = *(const bf16x8*)&Qbase[(size_t)(qs*16 + l15)*HD_ + ks*32 + quad*8];

    f32x4 cacc[4];
    #pragma unroll
    for (int j = 0; j < 4; j++) cacc[j] = (f32x4){0.f,0.f,0.f,0.f};
    float lac[4];
    #pragma unroll
    for (int qs = 0; qs < 4; qs++) lac[qs] = 0.f;

    const bf16* Kst = K + ((size_t)bh*S_ + w*8 + lr)*HD_ + lc*8;
    const bf16* Vst = Vt + ((size_t)bh*HD_ + w*8 + lr)*S_ + lc*8;

    // prologue: K(0), V(0)
    #pragma unroll
    for (int c = 0; c < 2; c++)
        gload16(Kst + (size_t)c*32*HD_, &Ks[0][c*2048 + w*512]);
    #pragma unroll
    for (int c = 0; c < 2; c++)
        gload16(Vst + (size_t)c*32*S_, &Vs[c*2048 + w*512]);
    __syncthreads();

    for (int it = 0; it < S_/64; it++) {
        const int cur = it & 1;
        const int k0 = it*64;

        // top-of-iter DMA
        if (it > 0) {
            #pragma unroll
            for (int c = 0; c < 2; c++)
                gload16(Vst + (size_t)c*32*S_ + k0, &Vs[c*2048 + w*512]);
        }
        if (it < S_/64 - 1) {
            #pragma unroll
            for (int c = 0; c < 2; c++)
                gload16(Kst + (size_t)(k0 + 64 + c*32)*HD_, &Ks[cur^1][c*2048 + w*512]);
        }

        // QK: S^T rows k in [w*16, w*16+16), all 64 q
        f32x4 st[4];
        #pragma unroll
        for (int qs = 0; qs < 4; qs++) st[qs] = (f32x4){0.f,0.f,0.f,0.f};
        #pragma unroll
        for (int ks = 0; ks < 2; ks++) {
            bf16x8 af = *(const bf16x8*)&Ks[cur][(w*16 + l15)*64 + (((ks*4+quad)^sx)*8)];
            #pragma unroll
            for (int qs = 0; qs < 4; qs++)
                st[qs] = __builtin_amdgcn_mfma_f32_16x16x32_bf16(af, qf[qs][ks], st[qs], 0, 0, 0);
        }

        // mask + polynomial sigmoid + P write (k = k0 + w*16 + quad*4 + r)
        float4 m4 = *(const float4*)&mask[(size_t)b*S_ + k0 + w*16 + quad*4];
        float mv[4] = {(1.0f-m4.x)*-10000.0f, (1.0f-m4.y)*-10000.0f,
                       (1.0f-m4.z)*-10000.0f, (1.0f-m4.w)*-10000.0f};
        const int c8 = (w*2 + (quad>>1)) ^ sx;
        #pragma unroll
        for (int qs = 0; qs < 4; qs++) {
            union { bf16 h4[4]; uint2 u; } pk;
            #pragma unroll
            for (int r = 0; r < 4; r++) {
                float s = st[qs][r] + mv[r];
                float c = __builtin_amdgcn_fmed3f(s, -3.0f, 3.0f);
                float u = fmaf(c*c, -0.01f, 0.25f);
                float sg = fmaf(c, u, 0.5f);
                sg = __builtin_amdgcn_fmed3f(sg, 0.01f, 0.99f);
                lac[qs] += sg;
                pk.h4[r] = (bf16)sg;
            }
            *(uint2*)&Ps[(qs*16 + l15)*64 + c8*8 + (quad&1)*4] = pk.u;
        }
        __syncthreads();   // B1: P visible; V(it)/K(it+1) DMA drained

        // PV: wave owns q in [w*16, w*16+16)
        #pragma unroll
        for (int ks = 0; ks < 2; ks++) {
            bf16x8 pf, vf[4];
            pf = *(const bf16x8*)&Ps[(w*16 + l15)*64 + (((ks*4+quad)^sx)*8)];
            #pragma unroll
            for (int nt = 0; nt < 4; nt++)
                vf[nt] = *(const bf16x8*)&Vs[(nt*16 + l15)*64 + (((ks*4+quad)^sx)*8)];
            #pragma unroll
            for (int nt = 0; nt < 4; nt++)
                cacc[nt] = __builtin_amdgcn_mfma_f32_16x16x32_bf16(pf, vf[nt], cacc[nt], 0, 0, 0);
        }
        __syncthreads();   // B2: PV reads done -> next iter may overwrite Vs/Ps
    }

    // cross-wave row-sum reduce (each wave holds partial over its k subset)
    #pragma unroll
    for (int qs = 0; qs < 4; qs++) {
        float v = lac[qs];
        v += __shfl_xor(v, 16);
        v += __shfl_xor(v, 32);
        if (quad == 0) lsumP[w][qs*16 + l15] = v;
    }
    __syncthreads();

    // normalize + store ctx (wave's q in [w*16, w*16+16))
    #pragma unroll
    for (int r = 0; r < 4; r++) {
        int q = w*16 + quad*4 + r;
        float s = lsumP[0][q] + lsumP[1][q] + lsumP[2][q] + lsumP[3][q];
        float rinv = 1.0f / (s + 1e-8f);
        size_t row = (size_t)(b*S_ + q0 + q);
        #pragma unroll
        for (int nt = 0; nt < 4; nt++)
            Ctx[row*D_ + h*HD_ + nt*16 + l15] = (bf16)(cacc[nt][r] * rinv);
    }
}

extern "C" void kernel_launch(void* const* d_in, const int* in_sizes, int n_in,
                              void* d_out, int out_size, void* d_ws, size_t ws_size,
                              hipStream_t stream) {
    const float* hs   = (const float*)d_in[0];
    const float* mask = (const float*)d_in[1];
    const float* Wq   = (const float*)d_in[2];
    const float* bq   = (const float*)d_in[3];
    const float* Wk   = (const float*)d_in[4];
    const float* bk   = (const float*)d_in[5];
    const float* Wv   = (const float*)d_in[6];
    const float* bv   = (const float*)d_in[7];
    const float* Wo   = (const float*)d_in[8];
    const float* bo   = (const float*)d_in[9];
    float* out = (float*)d_out;

    char* ws = (char*)d_ws;
    const size_t MB = 1024*1024;
    bf16* hb   = (bf16*)(ws);            // [M_,D_]        8 MB
    bf16* wqb  = (bf16*)(ws + 8*MB);     // [D_,D_]        2 MB
    bf16* wkb  = (bf16*)(ws + 10*MB);
    bf16* wvb  = (bf16*)(ws + 12*MB);
    bf16* wob  = (bf16*)(ws + 14*MB);
    bf16* qb   = (bf16*)(ws + 16*MB);    // [BH][S][HD]    8 MB
    bf16* kb   = (bf16*)(ws + 24*MB);    // [BH][S][HD]    8 MB
    bf16* vtb  = (bf16*)(ws + 32*MB);    // [BH][HD][S]    8 MB
    bf16* ctxb = (bf16*)(ws + 40*MB);    // [M_,D_]        8 MB

    k_cvt_all<<<2048 + 4*512, 256, 0, stream>>>(hs, Wq, Wk, Wv, Wo, hb, wqb, wkb, wvb, wob);

    k_gemm_qkv<<<dim3(D_/128, M_/128, 3), 256, 0, stream>>>(
        hb, wqb, wkb, wvb, bq, bk, bv, qb, kb, vtb);

    k_attn<<<dim3(S_/64, B_*H_), 256, 0, stream>>>(qb, kb, vtb, mask, ctxb);

    k_gemm_out<<<dim3(D_/128, M_/64), 256, 0, stream>>>(ctxb, wob, bo, out);
}

// Round 8
// 212.953 us; speedup vs baseline: 1.3092x; 1.1242x over previous
//
#include <hip/hip_runtime.h>
#include <stdint.h>

#define B_ 2
#define S_ 2048
#define D_ 1024
#define H_ 16
#define HD_ 64
#define M_ (B_*S_)   // 4096

typedef __bf16 bf16;
typedef __attribute__((ext_vector_type(8))) __bf16 bf16x8;
typedef __attribute__((ext_vector_type(4))) float f32x4;
typedef __attribute__((ext_vector_type(2))) float f32x2;

// async global->LDS, 16B per lane. LDS dest = uniform base + lane*16.
__device__ __forceinline__ void gload16(const bf16* g, bf16* l) {
    __builtin_amdgcn_global_load_lds(
        (const __attribute__((address_space(1))) void*)g,
        (__attribute__((address_space(3))) void*)l, 16, 0, 0);
}

// ---------------- fp32 -> bf16 converts (single launch) ----------------
__global__ void k_cvt_all(const float* __restrict__ hs,
                          const float* __restrict__ Wq, const float* __restrict__ Wk,
                          const float* __restrict__ Wv, const float* __restrict__ Wo,
                          bf16* __restrict__ hb,
                          bf16* __restrict__ wqb, bf16* __restrict__ wkb,
                          bf16* __restrict__ wvb, bf16* __restrict__ wob) {
    int blk = blockIdx.x;
    const float* s; bf16* d; int base;
    if (blk < 2048) { s = hs; d = hb; base = blk; }
    else {
        int r = blk - 2048; int which = r >> 9; base = r & 511;
        s = (which==0)?Wq:(which==1)?Wk:(which==2)?Wv:Wo;
        d = (which==0)?wqb:(which==1)?wkb:(which==2)?wvb:wob;
    }
    int idx = base*2048 + threadIdx.x*8;
    float4 a = *(const float4*)(s + idx);
    float4 b = *(const float4*)(s + idx + 4);
    bf16 o[8] = {(bf16)a.x,(bf16)a.y,(bf16)a.z,(bf16)a.w,
                 (bf16)b.x,(bf16)b.y,(bf16)b.z,(bf16)b.w};
    *(int4*)(d + idx) = *(const int4*)o;
}

// ---------------- QKV projection GEMM (coalesced LDS-transpose epilogue) ----
// z=0: Q -> [BH][S][HD] scaled 1/8 ; z=1: K -> [BH][S][HD] ; z=2: V -> [BH][HD][S]
__global__ __launch_bounds__(256) void k_gemm_qkv(
    const bf16* __restrict__ X,
    const bf16* __restrict__ Wq, const bf16* __restrict__ Wk, const bf16* __restrict__ Wv,
    const float* __restrict__ bq, const float* __restrict__ bk, const float* __restrict__ bv,
    bf16* __restrict__ Qo, bf16* __restrict__ Ko, bf16* __restrict__ Vo)
{
    const int z = blockIdx.z;
    const bf16* W = (z==0) ? Wq : (z==1) ? Wk : Wv;
    const float* bias = (z==0) ? bq : (z==1) ? bk : bv;
    const int n0 = blockIdx.x * 128;
    const int m0 = blockIdx.y * 128;
    const int t = threadIdx.x;
    const int w = t >> 6, lane = t & 63, quad = lane >> 4, l15 = lane & 15;
    const int lr = lane >> 3;
    const int lc = (lane & 7) ^ lr;
    const int sx = l15 & 7;
    const int mw = (w >> 1) * 64, nw = (w & 1) * 64;

    __shared__ __align__(16) char smraw[128*136*2];  // 34816 B, aliased
    bf16* As  = (bf16*)smraw;               // [128][64]
    bf16* Bs  = (bf16*)(smraw + 16384);     // [128][64]
    bf16* epi = (bf16*)smraw;               // [128][136]

    f32x4 acc[4][4];
    #pragma unroll
    for (int i = 0; i < 4; i++)
        #pragma unroll
        for (int j = 0; j < 4; j++)
            acc[i][j] = (f32x4){0.f,0.f,0.f,0.f};

    const bf16* gA = X + (size_t)(m0 + w*8 + lr)*D_ + lc*8;
    const bf16* gB = W + (size_t)(n0 + w*8 + lr)*D_ + lc*8;

    for (int k0 = 0; k0 < D_; k0 += 64) {
        #pragma unroll
        for (int c = 0; c < 4; c++) {
            gload16(gA + (size_t)c*32*D_ + k0, &As[c*2048 + w*512]);
            gload16(gB + (size_t)c*32*D_ + k0, &Bs[c*2048 + w*512]);
        }
        __syncthreads();
        #pragma unroll
        for (int ks = 0; ks < 2; ks++) {
            bf16x8 af[4], bfr[4];
            #pragma unroll
            for (int i = 0; i < 4; i++)
                af[i] = *(const bf16x8*)&As[(mw + i*16 + l15)*64 + (((ks*4+quad)^sx)*8)];
            #pragma unroll
            for (int j = 0; j < 4; j++)
                bfr[j] = *(const bf16x8*)&Bs[(nw + j*16 + l15)*64 + (((ks*4+quad)^sx)*8)];
            #pragma unroll
            for (int i = 0; i < 4; i++)
                #pragma unroll
                for (int j = 0; j < 4; j++)
                    acc[i][j] = __builtin_amdgcn_mfma_f32_16x16x32_bf16(af[i], bfr[j], acc[i][j], 0, 0, 0);
        }
        __syncthreads();
    }

    // ---- epilogue: acc -> LDS (transposed layouts) -> coalesced global ----
    const float scale = (z == 0) ? 0.125f : 1.0f;
    if (z == 2) {
        #pragma unroll
        for (int j = 0; j < 4; j++) {
            int n = nw + j*16 + l15;
            float bn = bias[n0 + n];
            #pragma unroll
            for (int i = 0; i < 4; i++) {
                int mloc = mw + i*16 + quad*4;
                union { bf16 h4[4]; uint2 u; } pk;
                #pragma unroll
                for (int r = 0; r < 4; r++) pk.h4[r] = (bf16)(acc[i][j][r] + bn);
                *(uint2*)&epi[n*136 + mloc] = pk.u;
            }
        }
    } else {
        #pragma unroll
        for (int j = 0; j < 4; j++) {
            int n = nw + j*16 + l15;
            float bn = bias[n0 + n];
            #pragma unroll
            for (int i = 0; i < 4; i++) {
                int mloc = mw + i*16 + quad*4;
                #pragma unroll
                for (int r = 0; r < 4; r++)
                    epi[(mloc + r)*136 + n] = (bf16)((acc[i][j][r] + bn) * scale);
            }
        }
    }
    __syncthreads();
    if (z == 2) {
        #pragma unroll
        for (int kk = 0; kk < 8; kk++) {
            int c = t + 256*kk;
            int row = c >> 4;             // local n (dim)
            int mcol = (c & 15) * 8;      // local m (token)
            int4 val = *(const int4*)&epi[row*136 + mcol];
            int n = n0 + row; int hh = n >> 6, hd = n & 63;
            int m = m0 + mcol; int bb = m >> 11, s = m & 2047;
            *(int4*)&Vo[((size_t)((bb*H_ + hh)*HD_ + hd))*S_ + s] = val;
        }
    } else {
        bf16* Out = (z == 0) ? Qo : Ko;
        #pragma unroll
        for (int kk = 0; kk < 8; kk++) {
            int c = t + 256*kk;
            int row = c >> 4;             // local m (token)
            int ncol = (c & 15) * 8;      // local n (dim)
            int4 val = *(const int4*)&epi[row*136 + ncol];
            int m = m0 + row; int bb = m >> 11, s = m & 2047;
            int n = n0 + ncol; int hh = n >> 6, hd = n & 63;
            *(int4*)&Out[((size_t)((bb*H_ + hh)*S_ + s))*HD_ + hd] = val;
        }
    }
}

// ---------------- output projection GEMM (64x128 tile, coalesced fp32 stores) --
__global__ __launch_bounds__(256) void k_gemm_out(
    const bf16* __restrict__ X, const bf16* __restrict__ W,
    const float* __restrict__ bias, float* __restrict__ Out)
{
    const int n0 = blockIdx.x * 128;
    const int m0 = blockIdx.y * 64;
    const int t = threadIdx.x;
    const int w = t >> 6, lane = t & 63, quad = lane >> 4, l15 = lane & 15;
    const int lr = lane >> 3;
    const int lc = (lane & 7) ^ lr;
    const int sx = l15 & 7;
    const int nw = w * 32;

    __shared__ __align__(16) char smraw[64*130*4];   // 33280 B, aliased
    bf16*  As  = (bf16*)smraw;              // [64][64]
    bf16*  Bs  = (bf16*)(smraw + 8192);     // [128][64]
    float* epi = (float*)smraw;             // [64][130] fp32

    f32x4 acc[4][2];
    #pragma unroll
    for (int i = 0; i < 4; i++)
        #pragma unroll
        for (int j = 0; j < 2; j++)
            acc[i][j] = (f32x4){0.f,0.f,0.f,0.f};

    const bf16* gA = X + (size_t)(m0 + w*8 + lr)*D_ + lc*8;
    const bf16* gB = W + (size_t)(n0 + w*8 + lr)*D_ + lc*8;

    for (int k0 = 0; k0 < D_; k0 += 64) {
        #pragma unroll
        for (int c = 0; c < 2; c++)
            gload16(gA + (size_t)c*32*D_ + k0, &As[c*2048 + w*512]);
        #pragma unroll
        for (int c = 0; c < 4; c++)
            gload16(gB + (size_t)c*32*D_ + k0, &Bs[c*2048 + w*512]);
        __syncthreads();
        #pragma unroll
        for (int ks = 0; ks < 2; ks++) {
            bf16x8 af[4], bfr[2];
            #pragma unroll
            for (int i = 0; i < 4; i++)
                af[i] = *(const bf16x8*)&As[(i*16 + l15)*64 + (((ks*4+quad)^sx)*8)];
            #pragma unroll
            for (int j = 0; j < 2; j++)
                bfr[j] = *(const bf16x8*)&Bs[(nw + j*16 + l15)*64 + (((ks*4+quad)^sx)*8)];
            #pragma unroll
            for (int i = 0; i < 4; i++)
                #pragma unroll
                for (int j = 0; j < 2; j++)
                    acc[i][j] = __builtin_amdgcn_mfma_f32_16x16x32_bf16(af[i], bfr[j], acc[i][j], 0, 0, 0);
        }
        __syncthreads();
    }

    // epilogue: acc (+bias) -> LDS fp32 [64][130] -> coalesced float4 stores
    #pragma unroll
    for (int j = 0; j < 2; j++) {
        int n = nw + j*16 + l15;
        float bn = bias[n0 + n];
        #pragma unroll
        for (int i = 0; i < 4; i++) {
            int row = i*16 + quad*4;
            #pragma unroll
            for (int r = 0; r < 4; r++)
                epi[(row + r)*130 + n] = acc[i][j][r] + bn;
        }
    }
    __syncthreads();
    #pragma unroll
    for (int kk = 0; kk < 8; kk++) {
        int c = t + 256*kk;
        int row = c >> 5;            // local m
        int cq  = (c & 31) * 4;      // local n (float4 granule)
        float2 v0 = *(const float2*)&epi[row*130 + cq];
        float2 v1 = *(const float2*)&epi[row*130 + cq + 2];
        float4 v = {v0.x, v0.y, v1.x, v1.y};
        *(float4*)&Out[(size_t)(m0 + row)*D_ + n0 + cq] = v;
    }
}

// ---------------- fused attention v8: R3 structure + packed-f32x2 sigmoid ----
// Q-tile 128/block (512 blocks). QK^T k-split across waves (Q in regs),
// PV q-split. K/V double-buffered DMA. 2 barriers/iter (R3-proven).
__global__ __launch_bounds__(256, 2) void k_attn(
    const bf16* __restrict__ Q, const bf16* __restrict__ K, const bf16* __restrict__ Vt,
    const float* __restrict__ mask, bf16* __restrict__ Ctx)
{
    const int bh = blockIdx.y;
    const int b = bh >> 4, h = bh & 15;
    const int q0 = blockIdx.x * 128;
    const int t = threadIdx.x;
    const int w = t >> 6, lane = t & 63, quad = lane >> 4, l15 = lane & 15;
    const int lr = lane >> 3;
    const int lc = (lane & 7) ^ lr;
    const int sx = l15 & 7;

    __shared__ __align__(16) bf16 Ks[2][64*64];
    __shared__ __align__(16) bf16 Vs[2][64*64];
    __shared__ __align__(16) bf16 Ps[128*64];   // P[q][k], xor-swizzled rows
    __shared__ float lsumP[4][128];

    // Q fragments in registers: all 128 q rows (B-operand), 16 frags
    bf16x8 qf[8][2];
    const bf16* Qbase = Q + ((size_t)bh*S_ + q0)*HD_;
    #pragma unroll
    for (int qs = 0; qs < 8; qs++)
        #pragma unroll
        for (int ks = 0; ks < 2; ks++)
            qf[qs][ks] = *(const bf16x8*)&Qbase[(size_t)(qs*16 + l15)*HD_ + ks*32 + quad*8];

    f32x4 cacc[2][4];
    #pragma unroll
    for (int i = 0; i < 2; i++)
        #pragma unroll
        for (int j = 0; j < 4; j++)
            cacc[i][j] = (f32x4){0.f,0.f,0.f,0.f};
    f32x2 lac[8];
    #pragma unroll
    for (int qs = 0; qs < 8; qs++) lac[qs] = (f32x2){0.f, 0.f};

    const bf16* Kst = K + ((size_t)bh*S_ + w*8 + lr)*HD_ + lc*8;
    const bf16* Vst = Vt + ((size_t)bh*HD_ + w*8 + lr)*S_ + lc*8;

    // prologue: stage tile 0
    #pragma unroll
    for (int c = 0; c < 2; c++)
        gload16(Kst + (size_t)c*32*HD_, &Ks[0][c*2048 + w*512]);
    #pragma unroll
    for (int c = 0; c < 2; c++)
        gload16(Vst + (size_t)c*32*S_, &Vs[0][c*2048 + w*512]);
    __syncthreads();

    for (int it = 0; it < S_/64; it++) {
        const int cur = it & 1;
        const int k0 = it*64;

        // QK: S^T rows k in [w*16, w*16+16), all 128 q
        f32x4 st[8];
        #pragma unroll
        for (int qs = 0; qs < 8; qs++) st[qs] = (f32x4){0.f,0.f,0.f,0.f};
        #pragma unroll
        for (int ks = 0; ks < 2; ks++) {
            bf16x8 af = *(const bf16x8*)&Ks[cur][(w*16 + l15)*64 + (((ks*4+quad)^sx)*8)];
            #pragma unroll
            for (int qs = 0; qs < 8; qs++)
                st[qs] = __builtin_amdgcn_mfma_f32_16x16x32_bf16(af, qf[qs][ks], st[qs], 0, 0, 0);
        }

        // mask + packed-f32x2 polynomial sigmoid + P write
        float4 m4 = *(const float4*)&mask[(size_t)b*S_ + k0 + w*16 + quad*4];
        f32x2 mv01 = {(1.0f-m4.x)*-10000.0f, (1.0f-m4.y)*-10000.0f};
        f32x2 mv23 = {(1.0f-m4.z)*-10000.0f, (1.0f-m4.w)*-10000.0f};
        const int c8 = (w*2 + (quad>>1)) ^ sx;
        #pragma unroll
        for (int qs = 0; qs < 8; qs++) {
            f32x2 a = (f32x2){st[qs][0], st[qs][1]} + mv01;
            f32x2 bb2 = (f32x2){st[qs][2], st[qs][3]} + mv23;
            a   = __builtin_elementwise_min(__builtin_elementwise_max(a,   (f32x2)(-3.0f)), (f32x2)(3.0f));
            bb2 = __builtin_elementwise_min(__builtin_elementwise_max(bb2, (f32x2)(-3.0f)), (f32x2)(3.0f));
            f32x2 ga = a   * (a*a     * (f32x2)(-0.01f) + (f32x2)(0.25f)) + (f32x2)(0.5f);
            f32x2 gb = bb2 * (bb2*bb2 * (f32x2)(-0.01f) + (f32x2)(0.25f)) + (f32x2)(0.5f);
            ga = __builtin_elementwise_min(__builtin_elementwise_max(ga, (f32x2)(0.01f)), (f32x2)(0.99f));
            gb = __builtin_elementwise_min(__builtin_elementwise_max(gb, (f32x2)(0.01f)), (f32x2)(0.99f));
            lac[qs] += ga + gb;
            union { bf16 h4[4]; uint2 u; } pk;
            pk.h4[0] = (bf16)ga.x; pk.h4[1] = (bf16)ga.y;
            pk.h4[2] = (bf16)gb.x; pk.h4[3] = (bf16)gb.y;
            *(uint2*)&Ps[(qs*16 + l15)*64 + c8*8 + (quad&1)*4] = pk.u;
        }
        __syncthreads();   // B1: P visible to all; K-frag reads done

        // prefetch next K/V tile into other buffer (read by nobody now)
        if (it < S_/64 - 1) {
            const int nxt = cur ^ 1, k1 = k0 + 64;
            #pragma unroll
            for (int c = 0; c < 2; c++)
                gload16(Kst + (size_t)(k1 + c*32)*HD_, &Ks[nxt][c*2048 + w*512]);
            #pragma unroll
            for (int c = 0; c < 2; c++)
                gload16(Vst + (size_t)c*32*S_ + k1, &Vs[nxt][c*2048 + w*512]);
        }

        // PV: wave owns q in [w*32, w*32+32)
        #pragma unroll
        for (int ks = 0; ks < 2; ks++) {
            bf16x8 pf[2], vf[4];
            #pragma unroll
            for (int m2 = 0; m2 < 2; m2++)
                pf[m2] = *(const bf16x8*)&Ps[(w*32 + m2*16 + l15)*64 + (((ks*4+quad)^sx)*8)];
            #pragma unroll
            for (int nt = 0; nt < 4; nt++)
                vf[nt] = *(const bf16x8*)&Vs[cur][(nt*16 + l15)*64 + (((ks*4+quad)^sx)*8)];
            #pragma unroll
            for (int m2 = 0; m2 < 2; m2++)
                #pragma unroll
                for (int nt = 0; nt < 4; nt++)
                    cacc[m2][nt] = __builtin_amdgcn_mfma_f32_16x16x32_bf16(pf[m2], vf[nt], cacc[m2][nt], 0, 0, 0);
        }
        __syncthreads();   // B2: DMA drained; PV reads done
    }

    // cross-wave row-sum reduce (each wave holds partial over its k subset)
    #pragma unroll
    for (int qs = 0; qs < 8; qs++) {
        float v = lac[qs].x + lac[qs].y;
        v += __shfl_xor(v, 16);
        v += __shfl_xor(v, 32);
        if (quad == 0) lsumP[w][qs*16 + l15] = v;
    }
    __syncthreads();

    // normalize + store ctx
    #pragma unroll
    for (int m2 = 0; m2 < 2; m2++) {
        #pragma unroll
        for (int r = 0; r < 4; r++) {
            int q = w*32 + m2*16 + quad*4 + r;
            float s = lsumP[0][q] + lsumP[1][q] + lsumP[2][q] + lsumP[3][q];
            float rinv = 1.0f / (s + 1e-8f);
            size_t row = (size_t)(b*S_ + q0 + q);
            #pragma unroll
            for (int nt = 0; nt < 4; nt++)
                Ctx[row*D_ + h*HD_ + nt*16 + l15] = (bf16)(cacc[m2][nt][r] * rinv);
        }
    }
}

extern "C" void kernel_launch(void* const* d_in, const int* in_sizes, int n_in,
                              void* d_out, int out_size, void* d_ws, size_t ws_size,
                              hipStream_t stream) {
    const float* hs   = (const float*)d_in[0];
    const float* mask = (const float*)d_in[1];
    const float* Wq   = (const float*)d_in[2];
    const float* bq   = (const float*)d_in[3];
    const float* Wk   = (const float*)d_in[4];
    const float* bk   = (const float*)d_in[5];
    const float* Wv   = (const float*)d_in[6];
    const float* bv   = (const float*)d_in[7];
    const float* Wo   = (const float*)d_in[8];
    const float* bo   = (const float*)d_in[9];
    float* out = (float*)d_out;

    char* ws = (char*)d_ws;
    const size_t MB = 1024*1024;
    bf16* hb   = (bf16*)(ws);            // [M_,D_]        8 MB
    bf16* wqb  = (bf16*)(ws + 8*MB);     // [D_,D_]        2 MB
    bf16* wkb  = (bf16*)(ws + 10*MB);
    bf16* wvb  = (bf16*)(ws + 12*MB);
    bf16* wob  = (bf16*)(ws + 14*MB);
    bf16* qb   = (bf16*)(ws + 16*MB);    // [BH][S][HD]    8 MB
    bf16* kb   = (bf16*)(ws + 24*MB);    // [BH][S][HD]    8 MB
    bf16* vtb  = (bf16*)(ws + 32*MB);    // [BH][HD][S]    8 MB
    bf16* ctxb = (bf16*)(ws + 40*MB);    // [M_,D_]        8 MB

    k_cvt_all<<<2048 + 4*512, 256, 0, stream>>>(hs, Wq, Wk, Wv, Wo, hb, wqb, wkb, wvb, wob);

    k_gemm_qkv<<<dim3(D_/128, M_/128, 3), 256, 0, stream>>>(
        hb, wqb, wkb, wvb, bq, bk, bv, qb, kb, vtb);

    k_attn<<<dim3(S_/128, B_*H_), 256, 0, stream>>>(qb, kb, vtb, mask, ctxb);

    k_gemm_out<<<dim3(D_/128, M_/64), 256, 0, stream>>>(ctxb, wob, bo, out);
}